// Round 8
// baseline (413.022 us; speedup 1.0000x reference)
//
#include <hip/hip_runtime.h>

#define T_TOK 8192
#define DDIM 1024
#define HDIM 2048
#define NEXP 8

typedef __attribute__((ext_vector_type(8))) short short8;
typedef __attribute__((ext_vector_type(4))) float f32x4;

#define WAITV8 asm volatile("s_waitcnt vmcnt(8)" ::: "memory")
#define WAITV0 asm volatile("s_waitcnt vmcnt(0)" ::: "memory")
#define WAITL0 asm volatile("s_waitcnt lgkmcnt(0)" ::: "memory")
#define SCHEDB __builtin_amdgcn_sched_barrier(0)
#define BARRIER __builtin_amdgcn_s_barrier()

__device__ __forceinline__ unsigned short f2bf(float f) {
  unsigned int u = __builtin_bit_cast(unsigned int, f);
  u += 0x7fffu + ((u >> 16) & 1u);   // RNE
  return (unsigned short)(u >> 16);
}
__device__ __forceinline__ float bf2f(unsigned short h) {
  unsigned int u = ((unsigned int)h) << 16;
  return __builtin_bit_cast(float, u);
}
__device__ __forceinline__ void gload16(const void* g, void* l) {
  __builtin_amdgcn_global_load_lds((const __attribute__((address_space(1))) void*)g,
                                   (__attribute__((address_space(3))) void*)l, 16, 0, 0);
}
__device__ __forceinline__ int imin(int a, int b) { return a < b ? a : b; }

// ---------------- fp32 -> bf16 straight convert (x) ----------------
__global__ __launch_bounds__(256) void cvt_kernel(const float* __restrict__ in,
                                                  unsigned short* __restrict__ out, int n) {
  int i = (blockIdx.x * 256 + threadIdx.x) * 8;
  int stride = gridDim.x * 256 * 8;
  for (; i < n; i += stride) {
    float4 a = *(const float4*)(in + i);
    float4 b = *(const float4*)(in + i + 4);
    alignas(16) unsigned short t[8] = {f2bf(a.x), f2bf(a.y), f2bf(a.z), f2bf(a.w),
                                       f2bf(b.x), f2bf(b.y), f2bf(b.z), f2bf(b.w)};
    *(uint4*)(out + i) = *(const uint4*)t;
  }
}

// ------- fp32 [E][R][C] -> bf16 [E][C][R] transpose-convert, optional row-perm -------
// perm: out row = 32*(col>>4) + (col&15) + s16   (W1/W2 16-row interleave)
__global__ __launch_bounds__(256) void tcvt_kernel(const float* __restrict__ in,
                                                   unsigned short* __restrict__ out,
                                                   int R, int C, size_t outEstride,
                                                   int perm, int s16) {
  int e = blockIdx.z;
  int rb = blockIdx.y * 64, cb = blockIdx.x * 64;
  const float* inE = in + (size_t)e * R * C;
  unsigned short* outE = out + (size_t)e * outEstride;
  __shared__ float tile[64][65];
  int tid = threadIdx.x;
  #pragma unroll
  for (int i = 0; i < 4; ++i) {
    int f = tid + i * 256;
    int r = f >> 4, c4 = (f & 15) << 2;
    float4 v = *(const float4*)(inE + (size_t)(rb + r) * C + cb + c4);
    tile[r][c4] = v.x; tile[r][c4 + 1] = v.y; tile[r][c4 + 2] = v.z; tile[r][c4 + 3] = v.w;
  }
  __syncthreads();
  #pragma unroll
  for (int i = 0; i < 2; ++i) {
    int g = tid + i * 256;
    int oc = g >> 3;
    int r8 = (g & 7) << 3;
    alignas(16) unsigned short tmp[8];
    #pragma unroll
    for (int j = 0; j < 8; ++j) tmp[j] = f2bf(tile[r8 + j][oc]);
    int orow = cb + oc;
    int orow2 = perm ? (32 * (orow >> 4) + (orow & 15) + s16) : orow;
    *(uint4*)(outE + (size_t)orow2 * R + rb + r8) = *(const uint4*)tmp;
  }
}

// ---------------- gating: logits, softmax, top-2 (NO atomics) ----------------
__global__ __launch_bounds__(256) void gate_kernel(const float* __restrict__ x,
                                                   const float* __restrict__ gw,
                                                   int* __restrict__ t_exp,
                                                   float* __restrict__ t_w) {
  int t = blockIdx.x * 4 + (threadIdx.x >> 6);
  int lane = threadIdx.x & 63;
  const float* xp = x + (size_t)t * DDIM;
  float acc[NEXP];
  #pragma unroll
  for (int e = 0; e < NEXP; ++e) acc[e] = 0.f;
  for (int i = 0; i < DDIM / 64; ++i) {
    int d = i * 64 + lane;
    float xv = xp[d];
    const float* g = gw + d * NEXP;
    #pragma unroll
    for (int e = 0; e < NEXP; ++e) acc[e] += xv * g[e];
  }
  #pragma unroll
  for (int off = 32; off > 0; off >>= 1) {
    #pragma unroll
    for (int e = 0; e < NEXP; ++e) acc[e] += __shfl_xor(acc[e], off, 64);
  }
  float mx = acc[0];
  #pragma unroll
  for (int e = 1; e < NEXP; ++e) mx = fmaxf(mx, acc[e]);
  float p[NEXP]; float S = 0.f;
  #pragma unroll
  for (int e = 0; e < NEXP; ++e) { p[e] = expf(acc[e] - mx); S += p[e]; }
  int i0 = 0; float v0 = p[0];
  #pragma unroll
  for (int e = 1; e < NEXP; ++e) if (p[e] > v0) { v0 = p[e]; i0 = e; }
  int i1 = -1; float v1 = -1.f;
  #pragma unroll
  for (int e = 0; e < NEXP; ++e) if (e != i0 && p[e] > v1) { v1 = p[e]; i1 = e; }
  float pv0 = v0 / S, pv1 = v1 / S;
  float denom = pv0 + pv1 + 1e-9f;
  if (lane == 0) {
    t_exp[t * 2] = i0; t_exp[t * 2 + 1] = i1;
    t_w[t * 2] = pv0 / denom; t_w[t * 2 + 1] = pv1 / denom;
  }
}

// -------- deterministic partition: counts, offsets, stable scatter (NO atomics) ----
__global__ __launch_bounds__(1024) void partition_kernel(
    const int* __restrict__ t_exp, const float* __restrict__ t_w,
    int* __restrict__ ctrl, int* __restrict__ row_tok,
    float* __restrict__ row_w, int* __restrict__ inv_row) {
  int tid = threadIdx.x;
  int wv = tid >> 6, lane = tid & 63;
  __shared__ int wtot[16][8];
  __shared__ int wbase[16][8];
  __shared__ int soff[8];

  int t0 = tid * 8;
  int exps[16];
  int c[8];
  #pragma unroll
  for (int e = 0; e < 8; ++e) c[e] = 0;
  #pragma unroll
  for (int s = 0; s < 16; ++s) {
    exps[s] = t_exp[t0 * 2 + s];
    #pragma unroll
    for (int e = 0; e < 8; ++e) c[e] += (exps[s] == e);
  }
  int inc[8];
  #pragma unroll
  for (int e = 0; e < 8; ++e) inc[e] = c[e];
  #pragma unroll
  for (int d = 1; d < 64; d <<= 1) {
    #pragma unroll
    for (int e = 0; e < 8; ++e) {
      int v = __shfl_up(inc[e], d, 64);
      if (lane >= d) inc[e] += v;
    }
  }
  if (lane == 63) {
    #pragma unroll
    for (int e = 0; e < 8; ++e) wtot[wv][e] = inc[e];
  }
  __syncthreads();
  if (wv == 0 && lane < 16) {
    #pragma unroll
    for (int e = 0; e < 8; ++e) {
      int b = 0;
      for (int w = 0; w < 16; ++w)
        if (w < lane) b += wtot[w][e];
      wbase[lane][e] = b;
    }
  }
  __syncthreads();
  if (tid == 0) {
    int o = 0;
    #pragma unroll
    for (int e = 0; e < 8; ++e) {
      int tot = wbase[15][e] + wtot[15][e];
      ctrl[e] = tot; ctrl[8 + e] = o; soff[e] = o; o += tot;
    }
  }
  __syncthreads();
  int base[8];
  #pragma unroll
  for (int e = 0; e < 8; ++e) base[e] = soff[e] + wbase[wv][e] + (inc[e] - c[e]);
  #pragma unroll
  for (int s = 0; s < 16; ++s) {
    int ee = exps[s];
    float w = t_w[t0 * 2 + s];
    int pos = 0;
    #pragma unroll
    for (int e = 0; e < 8; ++e)
      if (ee == e) { pos = base[e]; base[e] = base[e] + 1; }
    row_tok[pos] = t0 + (s >> 1);
    row_w[pos] = w;
    inv_row[t0 * 2 + s] = pos;
  }
}

// ============ 256x256 grouped GEMM, BK=64, 8 waves, dbuf, counted vmcnt ============
// K-step: wait vm(8) -> bar -> issue ALL 24 ds_reads -> MFMA k0 (compiler emits
// lgkmcnt(12): k1 reads fly under k0 MFMAs) -> lgkm0 -> bar -> STG(t+2) -> MFMA k1
// (pure-reg, covers stage issue).  1 vm-wait, 2 barriers, no serial drain.

// ---------------- GEMM1: G = silu(X@W1) * (X@W2) * row_w (interleaved W12) ----
__global__ __launch_bounds__(512, 2) void gemm1_kernel(
    const unsigned short* __restrict__ xbf,   // [T][1024]
    const unsigned short* __restrict__ w12t,  // [E][4096][1024], 16-row interleave
    const int* __restrict__ row_tok, const float* __restrict__ row_w,
    const int* __restrict__ ctrl, unsigned short* __restrict__ G) {
  // grid 2048. xcd = bid&7 = expert. j=bid>>3: [1:0]=nt_in, [5:2]=mt0, [7:6]=ntg
  int bid = blockIdx.x;
  int e = bid & 7;
  int j = bid >> 3;
  int nt = ((j >> 6) << 2) | (j & 3);
  int mt0 = (j >> 2) & 15;
  int cnt = ctrl[e];
  if (mt0 * 256 >= cnt) return;
  int off = ctrl[8 + e];

  __shared__ unsigned short lds[2][2][256 * 64];  // [buf][A/B]

  int tid = threadIdx.x, lane = tid & 63;
  const unsigned short* w12e = w12t + (size_t)e * (4096 * 1024);

  int rr = tid >> 3, cc = tid & 7;
  int clog8 = (cc ^ (rr & 7)) * 8;
  const unsigned short* bp[4];
  #pragma unroll
  for (int r = 0; r < 4; ++r)
    bp[r] = w12e + (size_t)(nt * 256 + r * 64 + rr) * 1024 + clog8;

  int wid = tid >> 6, wr = wid >> 2, wc = wid & 3;
  int lr16 = lane & 15, hi = lane >> 4, rk = lr16 & 7;
  int k0o = (hi ^ rk) * 8;
  int k1o = ((4 | hi) ^ rk) * 8;
  int abase = (wr * 128 + lr16) * 64;
  int bbase = (wc * 64 + lr16) * 64;

#define STG1(B, KT) do { int _k = (KT) * 64;                              \
    gload16(ap[0] + _k, &lds[B][0][0] + (0 * 512 + tid) * 8);             \
    gload16(ap[1] + _k, &lds[B][0][0] + (1 * 512 + tid) * 8);             \
    gload16(ap[2] + _k, &lds[B][0][0] + (2 * 512 + tid) * 8);             \
    gload16(ap[3] + _k, &lds[B][0][0] + (3 * 512 + tid) * 8);             \
    gload16(bp[0] + _k, &lds[B][1][0] + (0 * 512 + tid) * 8);             \
    gload16(bp[1] + _k, &lds[B][1][0] + (1 * 512 + tid) * 8);             \
    gload16(bp[2] + _k, &lds[B][1][0] + (2 * 512 + tid) * 8);             \
    gload16(bp[3] + _k, &lds[B][1][0] + (3 * 512 + tid) * 8); } while (0)

#define READF(B, KO, AV, BV) do {                                         \
    const unsigned short* _A = &lds[B][0][0];                             \
    const unsigned short* _Bp = &lds[B][1][0];                            \
    _Pragma("unroll")                                                     \
    for (int m = 0; m < 8; ++m) AV[m] = *(const short8*)(_A + abase + m * 1024 + KO); \
    _Pragma("unroll")                                                     \
    for (int n = 0; n < 4; ++n) BV[n] = *(const short8*)(_Bp + bbase + n * 1024 + KO); } while (0)

#define MF(AV, BV) do {                                                   \
    __builtin_amdgcn_s_setprio(1);                                        \
    _Pragma("unroll")                                                     \
    for (int m = 0; m < 8; ++m)                                           \
      _Pragma("unroll")                                                   \
      for (int n = 0; n < 4; ++n)                                         \
        acc[m][n] = __builtin_amdgcn_mfma_f32_16x16x32_bf16(AV[m], BV[n], acc[m][n], 0, 0, 0); \
    __builtin_amdgcn_s_setprio(0); } while (0)

  #pragma unroll 1
  for (int mt = mt0; mt * 256 < cnt; mt += 16) {
    const unsigned short* ap[4];
    #pragma unroll
    for (int r = 0; r < 4; ++r) {
      int tok = row_tok[off + imin(mt * 256 + r * 64 + rr, cnt - 1)];
      ap[r] = xbf + (size_t)tok * 1024 + clog8;
    }
    f32x4 z = {0.f, 0.f, 0.f, 0.f};
    f32x4 acc[8][4];
    #pragma unroll
    for (int m = 0; m < 8; ++m)
      #pragma unroll
      for (int n = 0; n < 4; ++n) acc[m][n] = z;

    STG1(0, 0);
    STG1(1, 1);
    #pragma unroll 1
    for (int kt = 0; kt < 16; ++kt) {
      int cb = kt & 1;
      if (kt + 1 < 16) { WAITV8; } else { WAITV0; }
      SCHEDB;
      BARRIER;
      short8 av[8], bv[4], av2[8], bv2[4];
      READF(cb, k0o, av, bv);           // 12 ds_reads (k0 frags)
      READF(cb, k1o, av2, bv2);         // 12 more (k1 frags) — fly under MFMA k0
      MF(av, bv);                       // compiler: lgkmcnt(12) before first use
      WAITL0; SCHEDB;                   // all 24 retired -> safe to overwrite
      BARRIER;
      if (kt + 2 < 16) STG1(cb, kt + 2);
      SCHEDB;
      MF(av2, bv2);                     // pure-reg, covers stage issue/flight
    }

    // fused SwiGLU epilogue: frag pairs (0,1),(2,3) are (W1,W2) for same H cols
    #pragma unroll
    for (int m = 0; m < 8; ++m)
      #pragma unroll
      for (int jj = 0; jj < 4; ++jj) {
        int rl = mt * 256 + wr * 128 + m * 16 + hi * 4 + jj;
        if (rl < cnt) {
          float wrj = row_w[off + rl];
          size_t base = (size_t)(off + rl) * HDIM + nt * 128 + wc * 32 + lr16;
          float h1 = acc[m][0][jj], h2 = acc[m][1][jj];
          G[base] = f2bf((h1 / (1.f + __expf(-h1))) * h2 * wrj);
          h1 = acc[m][2][jj]; h2 = acc[m][3][jj];
          G[base + 16] = f2bf((h1 / (1.f + __expf(-h1))) * h2 * wrj);
        }
      }
  }
#undef STG1
}

// ---------------- GEMM2: Y = G @ W3 ----------------
__global__ __launch_bounds__(512, 2) void gemm2_kernel(
    const unsigned short* __restrict__ G,     // [16384][2048]
    const unsigned short* __restrict__ w3t,   // [E][1024][2048]
    const int* __restrict__ ctrl, unsigned short* __restrict__ Y) {
  // grid 512. xcd = bid&7 = expert. j=bid>>3: [1:0]=nt, [5:2]=mt0.
  int bid = blockIdx.x;
  int e = bid & 7;
  int j = bid >> 3;
  int nt = j & 3;
  int mt0 = j >> 2;
  int cnt = ctrl[e];
  if (mt0 * 256 >= cnt) return;
  int off = ctrl[8 + e];

  __shared__ unsigned short lds[2][2][256 * 64];

  int tid = threadIdx.x, lane = tid & 63;
  const unsigned short* w3e = w3t + (size_t)e * (1024 * 2048);

  int rr = tid >> 3, cc = tid & 7;
  int clog8 = (cc ^ (rr & 7)) * 8;
  const unsigned short* bp[4];
  #pragma unroll
  for (int r = 0; r < 4; ++r)
    bp[r] = w3e + (size_t)(nt * 256 + r * 64 + rr) * 2048 + clog8;

  int wid = tid >> 6, wr = wid >> 2, wc = wid & 3;
  int lr16 = lane & 15, hi = lane >> 4, rk = lr16 & 7;
  int k0o = (hi ^ rk) * 8;
  int k1o = ((4 | hi) ^ rk) * 8;
  int abase = (wr * 128 + lr16) * 64;
  int bbase = (wc * 64 + lr16) * 64;

#define STG2(B, KT) do { int _k = (KT) * 64;                              \
    gload16(ap[0] + _k, &lds[B][0][0] + (0 * 512 + tid) * 8);             \
    gload16(ap[1] + _k, &lds[B][0][0] + (1 * 512 + tid) * 8);             \
    gload16(ap[2] + _k, &lds[B][0][0] + (2 * 512 + tid) * 8);             \
    gload16(ap[3] + _k, &lds[B][0][0] + (3 * 512 + tid) * 8);             \
    gload16(bp[0] + _k, &lds[B][1][0] + (0 * 512 + tid) * 8);             \
    gload16(bp[1] + _k, &lds[B][1][0] + (1 * 512 + tid) * 8);             \
    gload16(bp[2] + _k, &lds[B][1][0] + (2 * 512 + tid) * 8);             \
    gload16(bp[3] + _k, &lds[B][1][0] + (3 * 512 + tid) * 8); } while (0)

  #pragma unroll 1
  for (int mt = mt0; mt * 256 < cnt; mt += 16) {
    const unsigned short* ap[4];
    #pragma unroll
    for (int r = 0; r < 4; ++r)
      ap[r] = G + (size_t)(off + imin(mt * 256 + r * 64 + rr, cnt - 1)) * 2048 + clog8;

    f32x4 z = {0.f, 0.f, 0.f, 0.f};
    f32x4 acc[8][4];
    #pragma unroll
    for (int m = 0; m < 8; ++m)
      #pragma unroll
      for (int n = 0; n < 4; ++n) acc[m][n] = z;

    STG2(0, 0);
    STG2(1, 1);
    #pragma unroll 1
    for (int kt = 0; kt < 32; ++kt) {
      int cb = kt & 1;
      if (kt + 1 < 32) { WAITV8; } else { WAITV0; }
      SCHEDB;
      BARRIER;
      short8 av[8], bv[4], av2[8], bv2[4];
      READF(cb, k0o, av, bv);
      READF(cb, k1o, av2, bv2);
      MF(av, bv);
      WAITL0; SCHEDB;
      BARRIER;
      if (kt + 2 < 32) STG2(cb, kt + 2);
      SCHEDB;
      MF(av2, bv2);
    }

    #pragma unroll
    for (int m = 0; m < 8; ++m)
      #pragma unroll
      for (int jj = 0; jj < 4; ++jj) {
        int rl = mt * 256 + wr * 128 + m * 16 + hi * 4 + jj;
        if (rl < cnt) {
          size_t yrow = (size_t)(off + rl) * DDIM + nt * 256 + wc * 64 + lr16;
          #pragma unroll
          for (int n = 0; n < 4; ++n) Y[yrow + n * 16] = f2bf(acc[m][n][jj]);
        }
      }
  }
#undef STG2
#undef READF
#undef MF
}

// ---------------- combine: out[t] = Y[rowA] + Y[rowB] ----------------
__global__ __launch_bounds__(256) void combine_kernel(const unsigned short* __restrict__ Y,
                                                      const int* __restrict__ inv_row,
                                                      float* __restrict__ out) {
  int gid = blockIdx.x * 256 + threadIdx.x;   // 8192 * 128
  int t = gid >> 7;
  int cidx = (gid & 127) * 8;
  int rA = inv_row[t * 2], rB = inv_row[t * 2 + 1];
  uint4 va = *(const uint4*)(Y + (size_t)rA * DDIM + cidx);
  uint4 vb = *(const uint4*)(Y + (size_t)rB * DDIM + cidx);
  const unsigned short* pa = (const unsigned short*)&va;
  const unsigned short* pb = (const unsigned short*)&vb;
  float4 o0, o1;
  o0.x = bf2f(pa[0]) + bf2f(pb[0]); o0.y = bf2f(pa[1]) + bf2f(pb[1]);
  o0.z = bf2f(pa[2]) + bf2f(pb[2]); o0.w = bf2f(pa[3]) + bf2f(pb[3]);
  o1.x = bf2f(pa[4]) + bf2f(pb[4]); o1.y = bf2f(pa[5]) + bf2f(pb[5]);
  o1.z = bf2f(pa[6]) + bf2f(pb[6]); o1.w = bf2f(pa[7]) + bf2f(pb[7]);
  float* op = out + (size_t)t * DDIM + cidx;
  *(float4*)op = o0;
  *(float4*)(op + 4) = o1;
}

extern "C" void kernel_launch(void* const* d_in, const int* in_sizes, int n_in,
                              void* d_out, int out_size, void* d_ws, size_t ws_size,
                              hipStream_t stream) {
  const float* x  = (const float*)d_in[0];
  const float* gw = (const float*)d_in[1];
  const float* w1 = (const float*)d_in[2];
  const float* w2 = (const float*)d_in[3];
  const float* w3 = (const float*)d_in[4];
  float* out = (float*)d_out;
  char* ws = (char*)d_ws;

  // workspace layout (bytes); total ~218.4 MB
  unsigned short* xbf  = (unsigned short*)(ws + 0);             // 16,777,216
  unsigned short* w12t = (unsigned short*)(ws + 16777216);      // 67,108,864
  unsigned short* w3t  = (unsigned short*)(ws + 83886080);      // 33,554,432
  unsigned short* G    = (unsigned short*)(ws + 117440512);     // 67,108,864
  unsigned short* Y    = (unsigned short*)(ws + 184549376);     // 33,554,432
  int*   row_tok = (int*)  (ws + 218103808);
  float* row_w   = (float*)(ws + 218169344);
  int*   inv_row = (int*)  (ws + 218234880);
  int*   t_exp   = (int*)  (ws + 218300416);
  float* t_w     = (float*)(ws + 218365952);
  int*   ctrl    = (int*)  (ws + 218431488);

  cvt_kernel<<<4096, 256, 0, stream>>>(x, xbf, T_TOK * DDIM);
  tcvt_kernel<<<dim3(32, 16, 8), 256, 0, stream>>>(w1, w12t, 1024, 2048,
                                                   (size_t)4096 * 1024, 1, 0);
  tcvt_kernel<<<dim3(32, 16, 8), 256, 0, stream>>>(w2, w12t, 1024, 2048,
                                                   (size_t)4096 * 1024, 1, 16);
  tcvt_kernel<<<dim3(16, 32, 8), 256, 0, stream>>>(w3, w3t, 2048, 1024,
                                                   (size_t)1024 * 2048, 0, 0);

  gate_kernel<<<2048, 256, 0, stream>>>(x, gw, t_exp, t_w);
  partition_kernel<<<1, 1024, 0, stream>>>(t_exp, t_w, ctrl, row_tok, row_w, inv_row);

  gemm1_kernel<<<2048, 512, 0, stream>>>(xbf, w12t, row_tok, row_w, ctrl, G);
  gemm2_kernel<<<512, 512, 0, stream>>>(G, w3t, ctrl, Y);
  combine_kernel<<<4096, 256, 0, stream>>>(Y, inv_row, out);
}

// Round 9
// 393.708 us; speedup vs baseline: 1.0491x; 1.0491x over previous
//
#include <hip/hip_runtime.h>

#define T_TOK 8192
#define DDIM 1024
#define HDIM 2048
#define NEXP 8

typedef __attribute__((ext_vector_type(8))) short short8;
typedef __attribute__((ext_vector_type(4))) float f32x4;

#define WAITV8 asm volatile("s_waitcnt vmcnt(8)" ::: "memory")
#define WAITV0 asm volatile("s_waitcnt vmcnt(0)" ::: "memory")
#define WAITL0 asm volatile("s_waitcnt lgkmcnt(0)" ::: "memory")
#define SCHEDB __builtin_amdgcn_sched_barrier(0)
#define BARRIER __builtin_amdgcn_s_barrier()

__device__ __forceinline__ unsigned short f2bf(float f) {
  unsigned int u = __builtin_bit_cast(unsigned int, f);
  u += 0x7fffu + ((u >> 16) & 1u);   // RNE
  return (unsigned short)(u >> 16);
}
__device__ __forceinline__ float bf2f(unsigned short h) {
  unsigned int u = ((unsigned int)h) << 16;
  return __builtin_bit_cast(float, u);
}
__device__ __forceinline__ void gload16(const void* g, void* l) {
  __builtin_amdgcn_global_load_lds((const __attribute__((address_space(1))) void*)g,
                                   (__attribute__((address_space(3))) void*)l, 16, 0, 0);
}
__device__ __forceinline__ int imin(int a, int b) { return a < b ? a : b; }

// ---------------- fp32 -> bf16 straight convert (x) ----------------
__global__ __launch_bounds__(256) void cvt_kernel(const float* __restrict__ in,
                                                  unsigned short* __restrict__ out, int n) {
  int i = (blockIdx.x * 256 + threadIdx.x) * 8;
  int stride = gridDim.x * 256 * 8;
  for (; i < n; i += stride) {
    float4 a = *(const float4*)(in + i);
    float4 b = *(const float4*)(in + i + 4);
    alignas(16) unsigned short t[8] = {f2bf(a.x), f2bf(a.y), f2bf(a.z), f2bf(a.w),
                                       f2bf(b.x), f2bf(b.y), f2bf(b.z), f2bf(b.w)};
    *(uint4*)(out + i) = *(const uint4*)t;
  }
}

// ------- fp32 [E][R][C] -> bf16 [E][C][R] transpose-convert, optional row-perm -------
// perm: out row = 32*(col>>4) + (col&15) + s16   (W1/W2 16-row interleave)
__global__ __launch_bounds__(256) void tcvt_kernel(const float* __restrict__ in,
                                                   unsigned short* __restrict__ out,
                                                   int R, int C, size_t outEstride,
                                                   int perm, int s16) {
  int e = blockIdx.z;
  int rb = blockIdx.y * 64, cb = blockIdx.x * 64;
  const float* inE = in + (size_t)e * R * C;
  unsigned short* outE = out + (size_t)e * outEstride;
  __shared__ float tile[64][65];
  int tid = threadIdx.x;
  #pragma unroll
  for (int i = 0; i < 4; ++i) {
    int f = tid + i * 256;
    int r = f >> 4, c4 = (f & 15) << 2;
    float4 v = *(const float4*)(inE + (size_t)(rb + r) * C + cb + c4);
    tile[r][c4] = v.x; tile[r][c4 + 1] = v.y; tile[r][c4 + 2] = v.z; tile[r][c4 + 3] = v.w;
  }
  __syncthreads();
  #pragma unroll
  for (int i = 0; i < 2; ++i) {
    int g = tid + i * 256;
    int oc = g >> 3;
    int r8 = (g & 7) << 3;
    alignas(16) unsigned short tmp[8];
    #pragma unroll
    for (int j = 0; j < 8; ++j) tmp[j] = f2bf(tile[r8 + j][oc]);
    int orow = cb + oc;
    int orow2 = perm ? (32 * (orow >> 4) + (orow & 15) + s16) : orow;
    *(uint4*)(outE + (size_t)orow2 * R + rb + r8) = *(const uint4*)tmp;
  }
}

// ---------------- gating: logits, softmax, top-2 (NO atomics) ----------------
__global__ __launch_bounds__(256) void gate_kernel(const float* __restrict__ x,
                                                   const float* __restrict__ gw,
                                                   int* __restrict__ t_exp,
                                                   float* __restrict__ t_w) {
  int t = blockIdx.x * 4 + (threadIdx.x >> 6);
  int lane = threadIdx.x & 63;
  const float* xp = x + (size_t)t * DDIM;
  float acc[NEXP];
  #pragma unroll
  for (int e = 0; e < NEXP; ++e) acc[e] = 0.f;
  for (int i = 0; i < DDIM / 64; ++i) {
    int d = i * 64 + lane;
    float xv = xp[d];
    const float* g = gw + d * NEXP;
    #pragma unroll
    for (int e = 0; e < NEXP; ++e) acc[e] += xv * g[e];
  }
  #pragma unroll
  for (int off = 32; off > 0; off >>= 1) {
    #pragma unroll
    for (int e = 0; e < NEXP; ++e) acc[e] += __shfl_xor(acc[e], off, 64);
  }
  float mx = acc[0];
  #pragma unroll
  for (int e = 1; e < NEXP; ++e) mx = fmaxf(mx, acc[e]);
  float p[NEXP]; float S = 0.f;
  #pragma unroll
  for (int e = 0; e < NEXP; ++e) { p[e] = expf(acc[e] - mx); S += p[e]; }
  int i0 = 0; float v0 = p[0];
  #pragma unroll
  for (int e = 1; e < NEXP; ++e) if (p[e] > v0) { v0 = p[e]; i0 = e; }
  int i1 = -1; float v1 = -1.f;
  #pragma unroll
  for (int e = 0; e < NEXP; ++e) if (e != i0 && p[e] > v1) { v1 = p[e]; i1 = e; }
  float pv0 = v0 / S, pv1 = v1 / S;
  float denom = pv0 + pv1 + 1e-9f;
  if (lane == 0) {
    t_exp[t * 2] = i0; t_exp[t * 2 + 1] = i1;
    t_w[t * 2] = pv0 / denom; t_w[t * 2 + 1] = pv1 / denom;
  }
}

// -------- deterministic partition: counts, offsets, stable scatter (NO atomics) ----
__global__ __launch_bounds__(1024) void partition_kernel(
    const int* __restrict__ t_exp, const float* __restrict__ t_w,
    int* __restrict__ ctrl, int* __restrict__ row_tok,
    float* __restrict__ row_w, int* __restrict__ inv_row) {
  int tid = threadIdx.x;
  int wv = tid >> 6, lane = tid & 63;
  __shared__ int wtot[16][8];
  __shared__ int wbase[16][8];
  __shared__ int soff[8];

  int t0 = tid * 8;
  int exps[16];
  int c[8];
  #pragma unroll
  for (int e = 0; e < 8; ++e) c[e] = 0;
  #pragma unroll
  for (int s = 0; s < 16; ++s) {
    exps[s] = t_exp[t0 * 2 + s];
    #pragma unroll
    for (int e = 0; e < 8; ++e) c[e] += (exps[s] == e);
  }
  int inc[8];
  #pragma unroll
  for (int e = 0; e < 8; ++e) inc[e] = c[e];
  #pragma unroll
  for (int d = 1; d < 64; d <<= 1) {
    #pragma unroll
    for (int e = 0; e < 8; ++e) {
      int v = __shfl_up(inc[e], d, 64);
      if (lane >= d) inc[e] += v;
    }
  }
  if (lane == 63) {
    #pragma unroll
    for (int e = 0; e < 8; ++e) wtot[wv][e] = inc[e];
  }
  __syncthreads();
  if (wv == 0 && lane < 16) {
    #pragma unroll
    for (int e = 0; e < 8; ++e) {
      int b = 0;
      for (int w = 0; w < 16; ++w)
        if (w < lane) b += wtot[w][e];
      wbase[lane][e] = b;
    }
  }
  __syncthreads();
  if (tid == 0) {
    int o = 0;
    #pragma unroll
    for (int e = 0; e < 8; ++e) {
      int tot = wbase[15][e] + wtot[15][e];
      ctrl[e] = tot; ctrl[8 + e] = o; soff[e] = o; o += tot;
    }
  }
  __syncthreads();
  int base[8];
  #pragma unroll
  for (int e = 0; e < 8; ++e) base[e] = soff[e] + wbase[wv][e] + (inc[e] - c[e]);
  #pragma unroll
  for (int s = 0; s < 16; ++s) {
    int ee = exps[s];
    float w = t_w[t0 * 2 + s];
    int pos = 0;
    #pragma unroll
    for (int e = 0; e < 8; ++e)
      if (ee == e) { pos = base[e]; base[e] = base[e] + 1; }
    row_tok[pos] = t0 + (s >> 1);
    row_w[pos] = w;
    inv_row[t0 * 2 + s] = pos;
  }
}

// ====== 256x256 grouped GEMM, BK=64 (2 K-halves of 32), 8 waves, 8-PHASE pipeline ======
// LDS [buf][A/B][kh][256x32] = 128KB. Per phase: 4-8 ds_read_b128 + stage 1 half-tile
// (2 global_load_lds) + barrier + lgkm0 + 16 MFMA + barrier. vmcnt(8) in even phases only.
// Stage rotation (iter = tiles {t,t+1}): p1:A1(t+1) p2:B1(t+1) p3:A0(t+2) p4:B0(t+2)
//                                        p5:A1(t+2) p6:B1(t+2) p7:A0(t+3) p8:B0(t+3)

#define PHASE(B, KS, MH, STG, DOVM) do {                                   \
    short8 av[4];                                                          \
    if (MH == 0) {                                                         \
      _Pragma("unroll")                                                    \
      for (int n = 0; n < 4; ++n)                                          \
        bv[n] = *(const short8*)(&lds[B][1][KS][0] + boff + n * 512);      \
    }                                                                      \
    _Pragma("unroll")                                                      \
    for (int m = 0; m < 4; ++m)                                            \
      av[m] = *(const short8*)(&lds[B][0][KS][0] + aoff + (MH * 4 + m) * 512); \
    STG;                                                                   \
    if (DOVM) { WAITV8; }                                                  \
    BARRIER;                                                               \
    WAITL0; SCHEDB;                                                        \
    __builtin_amdgcn_s_setprio(1);                                         \
    _Pragma("unroll")                                                      \
    for (int m = 0; m < 4; ++m)                                            \
      _Pragma("unroll")                                                    \
      for (int n = 0; n < 4; ++n)                                          \
        acc[MH * 4 + m][n] = __builtin_amdgcn_mfma_f32_16x16x32_bf16(av[m], bv[n], acc[MH * 4 + m][n], 0, 0, 0); \
    __builtin_amdgcn_s_setprio(0);                                         \
    BARRIER;                                                               \
} while (0)

#define STAGE_A(B, KH, KT) do { int _o = (KT) * 64 + (KH) * 32;            \
    gload16(aSrc0 + _o, &lds[B][0][KH][0] + tid * 8);                      \
    gload16(aSrc1 + _o, &lds[B][0][KH][0] + (512 + tid) * 8); } while (0)
#define STAGE_B(B, KH, KT) do { int _o = (KT) * 64 + (KH) * 32;            \
    gload16(bSrc0 + _o, &lds[B][1][KH][0] + tid * 8);                      \
    gload16(bSrc1 + _o, &lds[B][1][KH][0] + (512 + tid) * 8); } while (0)

#define K_PIPELINE(NT)                                                     \
  WAITV0;                                                                  \
  STAGE_A(0, 0, 0); STAGE_B(0, 0, 0);                                      \
  STAGE_A(0, 1, 0); STAGE_B(0, 1, 0);                                      \
  STAGE_A(1, 0, 1); STAGE_B(1, 0, 1);                                      \
  WAITV8; BARRIER;                                                         \
  _Pragma("unroll 1")                                                      \
  for (int kt = 0; kt < (NT); kt += 2) {                                   \
    int t1 = kt + 1;                                                       \
    int t2 = imin(kt + 2, (NT) - 1), t3 = imin(kt + 3, (NT) - 1);          \
    PHASE(0, 0, 0, STAGE_A(1, 1, t1), 0);                                  \
    PHASE(0, 0, 1, STAGE_B(1, 1, t1), 1);                                  \
    PHASE(0, 1, 0, STAGE_A(0, 0, t2), 0);                                  \
    PHASE(0, 1, 1, STAGE_B(0, 0, t2), 1);                                  \
    PHASE(1, 0, 0, STAGE_A(0, 1, t2), 0);                                  \
    PHASE(1, 0, 1, STAGE_B(0, 1, t2), 1);                                  \
    PHASE(1, 1, 0, STAGE_A(1, 0, t3), 0);                                  \
    PHASE(1, 1, 1, STAGE_B(1, 0, t3), 1);                                  \
  }

// ---------------- GEMM1: G = silu(X@W1) * (X@W2) * row_w (interleaved W12) ----
__global__ __launch_bounds__(512, 1) void gemm1_kernel(
    const unsigned short* __restrict__ xbf,   // [T][1024]
    const unsigned short* __restrict__ w12t,  // [E][4096][1024], 16-row interleave
    const int* __restrict__ row_tok, const float* __restrict__ row_w,
    const int* __restrict__ ctrl, unsigned short* __restrict__ G) {
  // grid 2048. xcd = bid&7 = expert. j=bid>>3: [1:0]=nt_in, [5:2]=mt0, [7:6]=ntg
  int bid = blockIdx.x;
  int e = bid & 7;
  int j = bid >> 3;
  int nt = ((j >> 6) << 2) | (j & 3);
  int mt0 = (j >> 2) & 15;
  int cnt = ctrl[e];
  if (mt0 * 256 >= cnt) return;
  int off = ctrl[8 + e];

  __shared__ unsigned short lds[2][2][2][8192];  // [buf][A/B][kh][256*32]

  int tid = threadIdx.x, lane = tid & 63;
  const unsigned short* w12e = w12t + (size_t)e * (4096 * 1024);

  // staging geometry: slot s (l*512+tid): row = s>>2, chunk = s&3; source chunk
  // pre-swizzled c ^ ((row>>1)&3)  (linear LDS dest, swizzled read — rule #21)
  int r0 = tid >> 2, c0 = tid & 3;
  int r1 = 128 + r0;
  int cs0 = (c0 ^ ((r0 >> 1) & 3)) * 8;
  int cs1 = (c0 ^ ((r1 >> 1) & 3)) * 8;
  const unsigned short* bSrc0 = w12e + (size_t)(nt * 256 + r0) * 1024 + cs0;
  const unsigned short* bSrc1 = w12e + (size_t)(nt * 256 + r1) * 1024 + cs1;

  int wid = tid >> 6, wr = wid >> 2, wc = wid & 3;
  int lr16 = lane & 15, hi = lane >> 4;
  int skey = (lr16 >> 1) & 3;
  int aoff = (wr * 128 + lr16) * 32 + ((hi ^ skey) * 8);
  int boff = (wc * 64 + lr16) * 32 + ((hi ^ skey) * 8);

  #pragma unroll 1
  for (int mt = mt0; mt * 256 < cnt; mt += 16) {
    int tokA = row_tok[off + imin(mt * 256 + r0, cnt - 1)];
    int tokB = row_tok[off + imin(mt * 256 + r1, cnt - 1)];
    const unsigned short* aSrc0 = xbf + (size_t)tokA * 1024 + cs0;
    const unsigned short* aSrc1 = xbf + (size_t)tokB * 1024 + cs1;

    f32x4 z = {0.f, 0.f, 0.f, 0.f};
    f32x4 acc[8][4];
    #pragma unroll
    for (int m = 0; m < 8; ++m)
      #pragma unroll
      for (int n = 0; n < 4; ++n) acc[m][n] = z;
    short8 bv[4];

    K_PIPELINE(16)

    // fused SwiGLU epilogue: frag pairs (0,1),(2,3) are (W1,W2) for same H cols
    #pragma unroll
    for (int m = 0; m < 8; ++m)
      #pragma unroll
      for (int jj = 0; jj < 4; ++jj) {
        int rl = mt * 256 + wr * 128 + m * 16 + hi * 4 + jj;
        if (rl < cnt) {
          float wrj = row_w[off + rl];
          size_t base = (size_t)(off + rl) * HDIM + nt * 128 + wc * 32 + lr16;
          float h1 = acc[m][0][jj], h2 = acc[m][1][jj];
          G[base] = f2bf((h1 / (1.f + __expf(-h1))) * h2 * wrj);
          h1 = acc[m][2][jj]; h2 = acc[m][3][jj];
          G[base + 16] = f2bf((h1 / (1.f + __expf(-h1))) * h2 * wrj);
        }
      }
  }
}

// ---------------- GEMM2: Y = G @ W3 ----------------
__global__ __launch_bounds__(512, 1) void gemm2_kernel(
    const unsigned short* __restrict__ G,     // [16384][2048]
    const unsigned short* __restrict__ w3t,   // [E][1024][2048]
    const int* __restrict__ ctrl, unsigned short* __restrict__ Y) {
  // grid 512. xcd = bid&7 = expert. j=bid>>3: [1:0]=nt, [5:2]=mt0.
  int bid = blockIdx.x;
  int e = bid & 7;
  int j = bid >> 3;
  int nt = j & 3;
  int mt0 = j >> 2;
  int cnt = ctrl[e];
  if (mt0 * 256 >= cnt) return;
  int off = ctrl[8 + e];

  __shared__ unsigned short lds[2][2][2][8192];

  int tid = threadIdx.x, lane = tid & 63;
  const unsigned short* w3e = w3t + (size_t)e * (1024 * 2048);

  int r0 = tid >> 2, c0 = tid & 3;
  int r1 = 128 + r0;
  int cs0 = (c0 ^ ((r0 >> 1) & 3)) * 8;
  int cs1 = (c0 ^ ((r1 >> 1) & 3)) * 8;
  const unsigned short* bSrc0 = w3e + (size_t)(nt * 256 + r0) * 2048 + cs0;
  const unsigned short* bSrc1 = w3e + (size_t)(nt * 256 + r1) * 2048 + cs1;

  int wid = tid >> 6, wr = wid >> 2, wc = wid & 3;
  int lr16 = lane & 15, hi = lane >> 4;
  int skey = (lr16 >> 1) & 3;
  int aoff = (wr * 128 + lr16) * 32 + ((hi ^ skey) * 8);
  int boff = (wc * 64 + lr16) * 32 + ((hi ^ skey) * 8);

  #pragma unroll 1
  for (int mt = mt0; mt * 256 < cnt; mt += 16) {
    const unsigned short* aSrc0 =
        G + (size_t)(off + imin(mt * 256 + r0, cnt - 1)) * 2048 + cs0;
    const unsigned short* aSrc1 =
        G + (size_t)(off + imin(mt * 256 + r1, cnt - 1)) * 2048 + cs1;

    f32x4 z = {0.f, 0.f, 0.f, 0.f};
    f32x4 acc[8][4];
    #pragma unroll
    for (int m = 0; m < 8; ++m)
      #pragma unroll
      for (int n = 0; n < 4; ++n) acc[m][n] = z;
    short8 bv[4];

    K_PIPELINE(32)

    #pragma unroll
    for (int m = 0; m < 8; ++m)
      #pragma unroll
      for (int jj = 0; jj < 4; ++jj) {
        int rl = mt * 256 + wr * 128 + m * 16 + hi * 4 + jj;
        if (rl < cnt) {
          size_t yrow = (size_t)(off + rl) * DDIM + nt * 256 + wc * 64 + lr16;
          #pragma unroll
          for (int n = 0; n < 4; ++n) Y[yrow + n * 16] = f2bf(acc[m][n][jj]);
        }
      }
  }
}

// ---------------- combine: out[t] = Y[rowA] + Y[rowB] ----------------
__global__ __launch_bounds__(256) void combine_kernel(const unsigned short* __restrict__ Y,
                                                      const int* __restrict__ inv_row,
                                                      float* __restrict__ out) {
  int gid = blockIdx.x * 256 + threadIdx.x;   // 8192 * 128
  int t = gid >> 7;
  int cidx = (gid & 127) * 8;
  int rA = inv_row[t * 2], rB = inv_row[t * 2 + 1];
  uint4 va = *(const uint4*)(Y + (size_t)rA * DDIM + cidx);
  uint4 vb = *(const uint4*)(Y + (size_t)rB * DDIM + cidx);
  const unsigned short* pa = (const unsigned short*)&va;
  const unsigned short* pb = (const unsigned short*)&vb;
  float4 o0, o1;
  o0.x = bf2f(pa[0]) + bf2f(pb[0]); o0.y = bf2f(pa[1]) + bf2f(pb[1]);
  o0.z = bf2f(pa[2]) + bf2f(pb[2]); o0.w = bf2f(pa[3]) + bf2f(pb[3]);
  o1.x = bf2f(pa[4]) + bf2f(pb[4]); o1.y = bf2f(pa[5]) + bf2f(pb[5]);
  o1.z = bf2f(pa[6]) + bf2f(pb[6]); o1.w = bf2f(pa[7]) + bf2f(pb[7]);
  float* op = out + (size_t)t * DDIM + cidx;
  *(float4*)op = o0;
  *(float4*)(op + 4) = o1;
}

extern "C" void kernel_launch(void* const* d_in, const int* in_sizes, int n_in,
                              void* d_out, int out_size, void* d_ws, size_t ws_size,
                              hipStream_t stream) {
  const float* x  = (const float*)d_in[0];
  const float* gw = (const float*)d_in[1];
  const float* w1 = (const float*)d_in[2];
  const float* w2 = (const float*)d_in[3];
  const float* w3 = (const float*)d_in[4];
  float* out = (float*)d_out;
  char* ws = (char*)d_ws;

  // workspace layout (bytes); total ~218.4 MB
  unsigned short* xbf  = (unsigned short*)(ws + 0);             // 16,777,216
  unsigned short* w12t = (unsigned short*)(ws + 16777216);      // 67,108,864
  unsigned short* w3t  = (unsigned short*)(ws + 83886080);      // 33,554,432
  unsigned short* G    = (unsigned short*)(ws + 117440512);     // 67,108,864
  unsigned short* Y    = (unsigned short*)(ws + 184549376);     // 33,554,432
  int*   row_tok = (int*)  (ws + 218103808);
  float* row_w   = (float*)(ws + 218169344);
  int*   inv_row = (int*)  (ws + 218234880);
  int*   t_exp   = (int*)  (ws + 218300416);
  float* t_w     = (float*)(ws + 218365952);
  int*   ctrl    = (int*)  (ws + 218431488);

  cvt_kernel<<<4096, 256, 0, stream>>>(x, xbf, T_TOK * DDIM);
  tcvt_kernel<<<dim3(32, 16, 8), 256, 0, stream>>>(w1, w12t, 1024, 2048,
                                                   (size_t)4096 * 1024, 1, 0);
  tcvt_kernel<<<dim3(32, 16, 8), 256, 0, stream>>>(w2, w12t, 1024, 2048,
                                                   (size_t)4096 * 1024, 1, 16);
  tcvt_kernel<<<dim3(16, 32, 8), 256, 0, stream>>>(w3, w3t, 2048, 1024,
                                                   (size_t)1024 * 2048, 0, 0);

  gate_kernel<<<2048, 256, 0, stream>>>(x, gw, t_exp, t_w);
  partition_kernel<<<1, 1024, 0, stream>>>(t_exp, t_w, ctrl, row_tok, row_w, inv_row);

  gemm1_kernel<<<2048, 512, 0, stream>>>(xbf, w12t, row_tok, row_w, ctrl, G);
  gemm2_kernel<<<512, 512, 0, stream>>>(G, w3t, ctrl, Y);
  combine_kernel<<<4096, 256, 0, stream>>>(Y, inv_row, out);
}

// Round 10
// 390.566 us; speedup vs baseline: 1.0575x; 1.0080x over previous
//
#include <hip/hip_runtime.h>

#define T_TOK 8192
#define DDIM 1024
#define HDIM 2048
#define NEXP 8

typedef __attribute__((ext_vector_type(8))) short short8;
typedef __attribute__((ext_vector_type(4))) float f32x4;

#define WAITV2 asm volatile("s_waitcnt vmcnt(2)" ::: "memory")
#define WAITV0 asm volatile("s_waitcnt vmcnt(0)" ::: "memory")
#define WAITL0 asm volatile("s_waitcnt lgkmcnt(0)" ::: "memory")
#define SCHEDB __builtin_amdgcn_sched_barrier(0)
#define BARRIER __builtin_amdgcn_s_barrier()

__device__ __forceinline__ unsigned short f2bf(float f) {
  unsigned int u = __builtin_bit_cast(unsigned int, f);
  u += 0x7fffu + ((u >> 16) & 1u);   // RNE
  return (unsigned short)(u >> 16);
}
__device__ __forceinline__ float bf2f(unsigned short h) {
  unsigned int u = ((unsigned int)h) << 16;
  return __builtin_bit_cast(float, u);
}
__device__ __forceinline__ void gload16(const void* g, void* l) {
  __builtin_amdgcn_global_load_lds((const __attribute__((address_space(1))) void*)g,
                                   (__attribute__((address_space(3))) void*)l, 16, 0, 0);
}
__device__ __forceinline__ int imin(int a, int b) { return a < b ? a : b; }

// ---------------- fp32 -> bf16 straight convert (x) ----------------
__global__ __launch_bounds__(256) void cvt_kernel(const float* __restrict__ in,
                                                  unsigned short* __restrict__ out, int n) {
  int i = (blockIdx.x * 256 + threadIdx.x) * 8;
  int stride = gridDim.x * 256 * 8;
  for (; i < n; i += stride) {
    float4 a = *(const float4*)(in + i);
    float4 b = *(const float4*)(in + i + 4);
    alignas(16) unsigned short t[8] = {f2bf(a.x), f2bf(a.y), f2bf(a.z), f2bf(a.w),
                                       f2bf(b.x), f2bf(b.y), f2bf(b.z), f2bf(b.w)};
    *(uint4*)(out + i) = *(const uint4*)t;
  }
}

// ------- fp32 [E][R][C] -> bf16 [E][C][R] transpose-convert, optional row-perm -------
__global__ __launch_bounds__(256) void tcvt_kernel(const float* __restrict__ in,
                                                   unsigned short* __restrict__ out,
                                                   int R, int C, size_t outEstride,
                                                   int perm, int s16) {
  int e = blockIdx.z;
  int rb = blockIdx.y * 64, cb = blockIdx.x * 64;
  const float* inE = in + (size_t)e * R * C;
  unsigned short* outE = out + (size_t)e * outEstride;
  __shared__ float tile[64][65];
  int tid = threadIdx.x;
  #pragma unroll
  for (int i = 0; i < 4; ++i) {
    int f = tid + i * 256;
    int r = f >> 4, c4 = (f & 15) << 2;
    float4 v = *(const float4*)(inE + (size_t)(rb + r) * C + cb + c4);
    tile[r][c4] = v.x; tile[r][c4 + 1] = v.y; tile[r][c4 + 2] = v.z; tile[r][c4 + 3] = v.w;
  }
  __syncthreads();
  #pragma unroll
  for (int i = 0; i < 2; ++i) {
    int g = tid + i * 256;
    int oc = g >> 3;
    int r8 = (g & 7) << 3;
    alignas(16) unsigned short tmp[8];
    #pragma unroll
    for (int j = 0; j < 8; ++j) tmp[j] = f2bf(tile[r8 + j][oc]);
    int orow = cb + oc;
    int orow2 = perm ? (32 * (orow >> 4) + (orow & 15) + s16) : orow;
    *(uint4*)(outE + (size_t)orow2 * R + rb + r8) = *(const uint4*)tmp;
  }
}

// ---------------- gating: logits, softmax, top-2 (NO atomics) ----------------
__global__ __launch_bounds__(256) void gate_kernel(const float* __restrict__ x,
                                                   const float* __restrict__ gw,
                                                   int* __restrict__ t_exp,
                                                   float* __restrict__ t_w) {
  int t = blockIdx.x * 4 + (threadIdx.x >> 6);
  int lane = threadIdx.x & 63;
  const float* xp = x + (size_t)t * DDIM;
  float acc[NEXP];
  #pragma unroll
  for (int e = 0; e < NEXP; ++e) acc[e] = 0.f;
  for (int i = 0; i < DDIM / 64; ++i) {
    int d = i * 64 + lane;
    float xv = xp[d];
    const float* g = gw + d * NEXP;
    #pragma unroll
    for (int e = 0; e < NEXP; ++e) acc[e] += xv * g[e];
  }
  #pragma unroll
  for (int off = 32; off > 0; off >>= 1) {
    #pragma unroll
    for (int e = 0; e < NEXP; ++e) acc[e] += __shfl_xor(acc[e], off, 64);
  }
  float mx = acc[0];
  #pragma unroll
  for (int e = 1; e < NEXP; ++e) mx = fmaxf(mx, acc[e]);
  float p[NEXP]; float S = 0.f;
  #pragma unroll
  for (int e = 0; e < NEXP; ++e) { p[e] = expf(acc[e] - mx); S += p[e]; }
  int i0 = 0; float v0 = p[0];
  #pragma unroll
  for (int e = 1; e < NEXP; ++e) if (p[e] > v0) { v0 = p[e]; i0 = e; }
  int i1 = -1; float v1 = -1.f;
  #pragma unroll
  for (int e = 0; e < NEXP; ++e) if (e != i0 && p[e] > v1) { v1 = p[e]; i1 = e; }
  float pv0 = v0 / S, pv1 = v1 / S;
  float denom = pv0 + pv1 + 1e-9f;
  if (lane == 0) {
    t_exp[t * 2] = i0; t_exp[t * 2 + 1] = i1;
    t_w[t * 2] = pv0 / denom; t_w[t * 2 + 1] = pv1 / denom;
  }
}

// -------- deterministic partition: counts, offsets, stable scatter (NO atomics) ----
__global__ __launch_bounds__(1024) void partition_kernel(
    const int* __restrict__ t_exp, const float* __restrict__ t_w,
    int* __restrict__ ctrl, int* __restrict__ row_tok,
    float* __restrict__ row_w, int* __restrict__ inv_row) {
  int tid = threadIdx.x;
  int wv = tid >> 6, lane = tid & 63;
  __shared__ int wtot[16][8];
  __shared__ int wbase[16][8];
  __shared__ int soff[8];

  int t0 = tid * 8;
  int exps[16];
  int c[8];
  #pragma unroll
  for (int e = 0; e < 8; ++e) c[e] = 0;
  #pragma unroll
  for (int s = 0; s < 16; ++s) {
    exps[s] = t_exp[t0 * 2 + s];
    #pragma unroll
    for (int e = 0; e < 8; ++e) c[e] += (exps[s] == e);
  }
  int inc[8];
  #pragma unroll
  for (int e = 0; e < 8; ++e) inc[e] = c[e];
  #pragma unroll
  for (int d = 1; d < 64; d <<= 1) {
    #pragma unroll
    for (int e = 0; e < 8; ++e) {
      int v = __shfl_up(inc[e], d, 64);
      if (lane >= d) inc[e] += v;
    }
  }
  if (lane == 63) {
    #pragma unroll
    for (int e = 0; e < 8; ++e) wtot[wv][e] = inc[e];
  }
  __syncthreads();
  if (wv == 0 && lane < 16) {
    #pragma unroll
    for (int e = 0; e < 8; ++e) {
      int b = 0;
      for (int w = 0; w < 16; ++w)
        if (w < lane) b += wtot[w][e];
      wbase[lane][e] = b;
    }
  }
  __syncthreads();
  if (tid == 0) {
    int o = 0;
    #pragma unroll
    for (int e = 0; e < 8; ++e) {
      int tot = wbase[15][e] + wtot[15][e];
      ctrl[e] = tot; ctrl[8 + e] = o; soff[e] = o; o += tot;
    }
  }
  __syncthreads();
  int base[8];
  #pragma unroll
  for (int e = 0; e < 8; ++e) base[e] = soff[e] + wbase[wv][e] + (inc[e] - c[e]);
  #pragma unroll
  for (int s = 0; s < 16; ++s) {
    int ee = exps[s];
    float w = t_w[t0 * 2 + s];
    int pos = 0;
    #pragma unroll
    for (int e = 0; e < 8; ++e)
      if (ee == e) { pos = base[e]; base[e] = base[e] + 1; }
    row_tok[pos] = t0 + (s >> 1);
    row_w[pos] = w;
    inv_row[t0 * 2 + s] = pos;
  }
}

// ====== 256x256 grouped GEMM, BK=64, 8 waves, 8-phase, FULL-LINE staging ======
// LDS [buf][A/B][256][64] bf16 (32KB/panel, 128KB total). Stage unit = 64-row
// quarter of full 128B rows (1 gload inst, all-full-line requests); 2 units/phase.
// Read swizzle: chunk=(kh*4+hi)^(row&7); source pre-swizzle (tid&7)^((tid>>3)&7).
// Rotation: p1-p4 stage buf1<-t+1 (BQ01,BQ23,AQ02,AQ13), p5-p8 stage buf0<-t+2.
// Every consumed quarter staged >=2 phases before read; uniform WAITV2/phase.

#define PHASE(B_, KS_, MH_, STG) do {                                      \
    short8 av[4];                                                          \
    if (MH_ == 0) {                                                        \
      _Pragma("unroll")                                                    \
      for (int n = 0; n < 4; ++n)                                          \
        bv[n] = *(const short8*)(&lds[B_][1][0] + bR + cK[KS_] + n * 1024);\
    }                                                                      \
    _Pragma("unroll")                                                      \
    for (int m = 0; m < 4; ++m)                                            \
      av[m] = *(const short8*)(&lds[B_][0][0] + aR + cK[KS_] + (MH_ * 4 + m) * 1024); \
    STG;                                                                   \
    WAITV2;                                                                \
    BARRIER;                                                               \
    WAITL0; SCHEDB;                                                        \
    __builtin_amdgcn_s_setprio(1);                                         \
    _Pragma("unroll")                                                      \
    for (int m = 0; m < 4; ++m)                                            \
      _Pragma("unroll")                                                    \
      for (int n = 0; n < 4; ++n)                                          \
        acc[MH_ * 4 + m][n] = __builtin_amdgcn_mfma_f32_16x16x32_bf16(av[m], bv[n], acc[MH_ * 4 + m][n], 0, 0, 0); \
    __builtin_amdgcn_s_setprio(0);                                         \
    BARRIER;                                                               \
} while (0)

#define K_PIPELINE(NT)                                                     \
  WAITV0;                                                                  \
  STB(0, 0, 0); STB(0, 1, 0); STB(0, 2, 0); STB(0, 3, 0);                  \
  STA(0, 0, 0); STA(0, 1, 0); STA(0, 2, 0); STA(0, 3, 0);                  \
  WAITV0; BARRIER;                                                         \
  _Pragma("unroll 1")                                                      \
  for (int kt = 0; kt < (NT); kt += 2) {                                   \
    int t1 = kt + 1;                                                       \
    int t2 = imin(kt + 2, (NT) - 1);                                       \
    PHASE(0, 0, 0, { STB(1, 0, t1); STB(1, 1, t1); });                     \
    PHASE(0, 0, 1, { STB(1, 2, t1); STB(1, 3, t1); });                     \
    PHASE(0, 1, 0, { STA(1, 0, t1); STA(1, 2, t1); });                     \
    PHASE(0, 1, 1, { STA(1, 1, t1); STA(1, 3, t1); });                     \
    PHASE(1, 0, 0, { STB(0, 0, t2); STB(0, 1, t2); });                     \
    PHASE(1, 0, 1, { STB(0, 2, t2); STB(0, 3, t2); });                     \
    PHASE(1, 1, 0, { STA(0, 0, t2); STA(0, 2, t2); });                     \
    PHASE(1, 1, 1, { STA(0, 1, t2); STA(0, 3, t2); });                     \
  }

// ---------------- GEMM1: G = silu(X@W1) * (X@W2) * row_w (interleaved W12) ----
__global__ __launch_bounds__(512, 1) void gemm1_kernel(
    const unsigned short* __restrict__ xbf,   // [T][1024]
    const unsigned short* __restrict__ w12t,  // [E][4096][1024], 16-row interleave
    const int* __restrict__ row_tok, const float* __restrict__ row_w,
    const int* __restrict__ ctrl, unsigned short* __restrict__ G) {
  // grid 1024. xcd = bid&7 = expert. j=bid>>3 in [0,128): nt_in=j&3, mt0=(j>>2)&7, ntg=j>>5
  int bid = blockIdx.x;
  int e = bid & 7;
  int j = bid >> 3;
  int nt = ((j >> 5) << 2) | (j & 3);
  int mt0 = (j >> 2) & 7;
  int cnt = ctrl[e];
  if (mt0 * 256 >= cnt) return;
  int off = ctrl[8 + e];

  __shared__ unsigned short lds[2][2][16384];  // [buf][A=0/B=1][256*64]

  int tid = threadIdx.x, lane = tid & 63;
  const unsigned short* w12e = w12t + (size_t)e * (4096 * 1024);

  // staging: inst covers 64 rows x 128B; thread -> (row = tid>>3, chunk = tid&7)
  int sr = tid >> 3;
  int cS8 = ((tid & 7) ^ (sr & 7)) * 8;
  const unsigned short* bQ = w12e + (size_t)(nt * 256 + sr) * 1024 + cS8;

  int wid = tid >> 6, wr = wid >> 2, wc = wid & 3;
  int lr16 = lane & 15, hi = lane >> 4;
  int cK[2] = { ((hi) ^ (lr16 & 7)) * 8, ((4 | hi) ^ (lr16 & 7)) * 8 };
  int aR = (wr * 128 + lr16) * 64;
  int bR = (wc * 64 + lr16) * 64;

#define STA(B_, Q_, KT) gload16(aQ[Q_] + (KT) * 64, &lds[B_][0][0] + (Q_) * 4096 + tid * 8)
#define STB(B_, Q_, KT) gload16(bQ + (Q_) * 65536 + (KT) * 64, &lds[B_][1][0] + (Q_) * 4096 + tid * 8)

  #pragma unroll 1
  for (int mt = mt0; mt * 256 < cnt; mt += 8) {
    const unsigned short* aQ[4];
    #pragma unroll
    for (int q = 0; q < 4; ++q) {
      int tok = row_tok[off + imin(mt * 256 + q * 64 + sr, cnt - 1)];
      aQ[q] = xbf + (size_t)tok * 1024 + cS8;
    }
    f32x4 z = {0.f, 0.f, 0.f, 0.f};
    f32x4 acc[8][4];
    #pragma unroll
    for (int m = 0; m < 8; ++m)
      #pragma unroll
      for (int n = 0; n < 4; ++n) acc[m][n] = z;
    short8 bv[4];

    K_PIPELINE(16)

    // fused SwiGLU epilogue: frag pairs (0,1),(2,3) are (W1,W2) for same H cols
    #pragma unroll
    for (int m = 0; m < 8; ++m)
      #pragma unroll
      for (int jj = 0; jj < 4; ++jj) {
        int rl = mt * 256 + ((m >> 2) ? (64 + wr * 128) : (wr * 128)) + (m & 3) * 16 + hi * 4 + jj;
        // NOTE: rows for acc[mh*4+m'] are wr*128 + mh*64 + m'*16 + hi*4 + jj
        rl = mt * 256 + wr * 128 + (m >> 2) * 64 + (m & 3) * 16 + hi * 4 + jj;
        if (rl < cnt) {
          float wrj = row_w[off + rl];
          size_t base = (size_t)(off + rl) * HDIM + nt * 128 + wc * 32 + lr16;
          float h1 = acc[m][0][jj], h2 = acc[m][1][jj];
          G[base] = f2bf((h1 / (1.f + __expf(-h1))) * h2 * wrj);
          h1 = acc[m][2][jj]; h2 = acc[m][3][jj];
          G[base + 16] = f2bf((h1 / (1.f + __expf(-h1))) * h2 * wrj);
        }
      }
  }
#undef STA
#undef STB
}

// ---------------- GEMM2: Y = G @ W3 ----------------
__global__ __launch_bounds__(512, 1) void gemm2_kernel(
    const unsigned short* __restrict__ G,     // [16384][2048]
    const unsigned short* __restrict__ w3t,   // [E][1024][2048]
    const int* __restrict__ ctrl, unsigned short* __restrict__ Y) {
  // grid 256. xcd = bid&7 = expert. j=bid>>3 in [0,32): mt0=j&7, nt=j>>3
  int bid = blockIdx.x;
  int e = bid & 7;
  int j = bid >> 3;
  int nt = j >> 3;
  int mt0 = j & 7;
  int cnt = ctrl[e];
  if (mt0 * 256 >= cnt) return;
  int off = ctrl[8 + e];

  __shared__ unsigned short lds[2][2][16384];

  int tid = threadIdx.x, lane = tid & 63;
  const unsigned short* w3e = w3t + (size_t)e * (1024 * 2048);

  int sr = tid >> 3;
  int cS8 = ((tid & 7) ^ (sr & 7)) * 8;
  const unsigned short* bQ = w3e + (size_t)(nt * 256 + sr) * 2048 + cS8;

  int wid = tid >> 6, wr = wid >> 2, wc = wid & 3;
  int lr16 = lane & 15, hi = lane >> 4;
  int cK[2] = { ((hi) ^ (lr16 & 7)) * 8, ((4 | hi) ^ (lr16 & 7)) * 8 };
  int aR = (wr * 128 + lr16) * 64;
  int bR = (wc * 64 + lr16) * 64;

#define STA(B_, Q_, KT) gload16(aQ[Q_] + (KT) * 64, &lds[B_][0][0] + (Q_) * 4096 + tid * 8)
#define STB(B_, Q_, KT) gload16(bQ + (Q_) * 131072 + (KT) * 64, &lds[B_][1][0] + (Q_) * 4096 + tid * 8)

  #pragma unroll 1
  for (int mt = mt0; mt * 256 < cnt; mt += 8) {
    const unsigned short* aQ[4];
    #pragma unroll
    for (int q = 0; q < 4; ++q)
      aQ[q] = G + (size_t)(off + imin(mt * 256 + q * 64 + sr, cnt - 1)) * 2048 + cS8;

    f32x4 z = {0.f, 0.f, 0.f, 0.f};
    f32x4 acc[8][4];
    #pragma unroll
    for (int m = 0; m < 8; ++m)
      #pragma unroll
      for (int n = 0; n < 4; ++n) acc[m][n] = z;
    short8 bv[4];

    K_PIPELINE(32)

    #pragma unroll
    for (int m = 0; m < 8; ++m)
      #pragma unroll
      for (int jj = 0; jj < 4; ++jj) {
        int rl = mt * 256 + wr * 128 + (m >> 2) * 64 + (m & 3) * 16 + hi * 4 + jj;
        if (rl < cnt) {
          size_t yrow = (size_t)(off + rl) * DDIM + nt * 256 + wc * 64 + lr16;
          #pragma unroll
          for (int n = 0; n < 4; ++n) Y[yrow + n * 16] = f2bf(acc[m][n][jj]);
        }
      }
  }
#undef STA
#undef STB
}

// ---------------- combine: out[t] = Y[rowA] + Y[rowB] ----------------
__global__ __launch_bounds__(256) void combine_kernel(const unsigned short* __restrict__ Y,
                                                      const int* __restrict__ inv_row,
                                                      float* __restrict__ out) {
  int gid = blockIdx.x * 256 + threadIdx.x;   // 8192 * 128
  int t = gid >> 7;
  int cidx = (gid & 127) * 8;
  int rA = inv_row[t * 2], rB = inv_row[t * 2 + 1];
  uint4 va = *(const uint4*)(Y + (size_t)rA * DDIM + cidx);
  uint4 vb = *(const uint4*)(Y + (size_t)rB * DDIM + cidx);
  const unsigned short* pa = (const unsigned short*)&va;
  const unsigned short* pb = (const unsigned short*)&vb;
  float4 o0, o1;
  o0.x = bf2f(pa[0]) + bf2f(pb[0]); o0.y = bf2f(pa[1]) + bf2f(pb[1]);
  o0.z = bf2f(pa[2]) + bf2f(pb[2]); o0.w = bf2f(pa[3]) + bf2f(pb[3]);
  o1.x = bf2f(pa[4]) + bf2f(pb[4]); o1.y = bf2f(pa[5]) + bf2f(pb[5]);
  o1.z = bf2f(pa[6]) + bf2f(pb[6]); o1.w = bf2f(pa[7]) + bf2f(pb[7]);
  float* op = out + (size_t)t * DDIM + cidx;
  *(float4*)op = o0;
  *(float4*)(op + 4) = o1;
}

extern "C" void kernel_launch(void* const* d_in, const int* in_sizes, int n_in,
                              void* d_out, int out_size, void* d_ws, size_t ws_size,
                              hipStream_t stream) {
  const float* x  = (const float*)d_in[0];
  const float* gw = (const float*)d_in[1];
  const float* w1 = (const float*)d_in[2];
  const float* w2 = (const float*)d_in[3];
  const float* w3 = (const float*)d_in[4];
  float* out = (float*)d_out;
  char* ws = (char*)d_ws;

  // workspace layout (bytes); total ~218.4 MB
  unsigned short* xbf  = (unsigned short*)(ws + 0);             // 16,777,216
  unsigned short* w12t = (unsigned short*)(ws + 16777216);      // 67,108,864
  unsigned short* w3t  = (unsigned short*)(ws + 83886080);      // 33,554,432
  unsigned short* G    = (unsigned short*)(ws + 117440512);     // 67,108,864
  unsigned short* Y    = (unsigned short*)(ws + 184549376);     // 33,554,432
  int*   row_tok = (int*)  (ws + 218103808);
  float* row_w   = (float*)(ws + 218169344);
  int*   inv_row = (int*)  (ws + 218234880);
  int*   t_exp   = (int*)  (ws + 218300416);
  float* t_w     = (float*)(ws + 218365952);
  int*   ctrl    = (int*)  (ws + 218431488);

  cvt_kernel<<<4096, 256, 0, stream>>>(x, xbf, T_TOK * DDIM);
  tcvt_kernel<<<dim3(32, 16, 8), 256, 0, stream>>>(w1, w12t, 1024, 2048,
                                                   (size_t)4096 * 1024, 1, 0);
  tcvt_kernel<<<dim3(32, 16, 8), 256, 0, stream>>>(w2, w12t, 1024, 2048,
                                                   (size_t)4096 * 1024, 1, 16);
  tcvt_kernel<<<dim3(16, 32, 8), 256, 0, stream>>>(w3, w3t, 2048, 1024,
                                                   (size_t)1024 * 2048, 0, 0);

  gate_kernel<<<2048, 256, 0, stream>>>(x, gw, t_exp, t_w);
  partition_kernel<<<1, 1024, 0, stream>>>(t_exp, t_w, ctrl, row_tok, row_w, inv_row);

  gemm1_kernel<<<1024, 512, 0, stream>>>(xbf, w12t, row_tok, row_w, ctrl, G);
  gemm2_kernel<<<256, 512, 0, stream>>>(G, w3t, ctrl, Y);
  combine_kernel<<<4096, 256, 0, stream>>>(Y, inv_row, out);
}